// Round 1
// baseline (266.528 us; speedup 1.0000x reference)
//
#include <hip/hip_runtime.h>
#include <math.h>

#define T_DIM 128
#define H_DIM 16
#define N_DIM 64
#define C_DIM 256
#define S_DIM 129   // 2*64+1
#define LOG_TINY (-87.336544750553109f)

__device__ __forceinline__ float logadd_(float a, float b) {
    float m = fmaxf(a, b);
    float d = fminf(a, b) - m;          // <= 0
    return m + __logf(1.0f + __expf(d));
}

// Kernel 1: Gc[t][n][c] = logsumexp_h( classify[t,h,n,c] + mask[t,h,n] )
// Fully coalesced read of classify (134 MB) -> memory-bound.
__global__ __launch_bounds__(256) void gc_kernel(
    const float* __restrict__ mask,        // (T,H,N)
    const float* __restrict__ classify,    // (T,H,N,C)
    float* __restrict__ Gc)                // (T,N,C)
{
    const int b = blockIdx.x;
    const int t = b >> 6;        // /64
    const int n = b & 63;
    const int c = threadIdx.x;   // 0..255

    __shared__ float m_lds[H_DIM];
    if (threadIdx.x < H_DIM)
        m_lds[threadIdx.x] = mask[(t * H_DIM + threadIdx.x) * N_DIM + n];
    __syncthreads();

    const float* base = classify + ((size_t)t * H_DIM * N_DIM + n) * C_DIM + c;

    float x[H_DIM];
    float mx = -3.4e38f;
#pragma unroll
    for (int h = 0; h < H_DIM; ++h) {
        x[h] = base[(size_t)h * N_DIM * C_DIM] + m_lds[h];
        mx = fmaxf(mx, x[h]);
    }
    float s = 0.f;
#pragma unroll
    for (int h = 0; h < H_DIM; ++h)
        s += __expf(x[h] - mx);

    Gc[((size_t)t * N_DIM + n) * C_DIM + c] = mx + __logf(s);
}

// Kernel 2: sequential CTC lattice scan. One block per n, thread s owns
// lattice position s. 127 steps, one __syncthreads per step (double-buffered
// LDS for the hs neighbor exchange), G prefetched one step ahead.
__global__ __launch_bounds__(192) void scan_kernel(
    const float* __restrict__ Gc,        // (T,N,C)
    const int*   __restrict__ targets,   // (N,64)
    const int*   __restrict__ tlen,      // (N,)
    float*       __restrict__ out)       // (N,)
{
    const int n = blockIdx.x;
    const int s = threadIdx.x;           // 0..191, active: 0..128

    __shared__ float hsbuf[2][S_DIM + 3];
    __shared__ unsigned char skip_lds[T_DIM - 1];   // mask_skip[j], j=0..126
    __shared__ float resbuf[S_DIM];

    // et[n,s]: even s -> blank(0); odd s -> targets[n][s>>1]
    int et = 0;
    if (s < S_DIM && (s & 1)) et = targets[n * 64 + (s >> 1)];

    // mask_skip[j] = (et[j+2] != et[j]); nonzero only for odd j
    if (s < T_DIM - 1) {
        int v = 0;
        if (s & 1)
            v = (targets[n * 64 + ((s + 1) >> 1)] !=
                 targets[n * 64 + ((s - 1) >> 1)]) ? 1 : 0;
        skip_lds[s] = (unsigned char)v;
    }
    __syncthreads();

    int skip_s = 0;
    if (s >= 2 && s < S_DIM) skip_s = skip_lds[s - 2];

    // v encodes p0: s<2 -> 0 (hs = G[0,s] clamped); s>=2 -> dead (clamps to LOG_TINY)
    float v = (s < 2) ? 0.f : -1e30f;

    const float* gptr = Gc + (size_t)n * C_DIM + et;
    float g = (s < S_DIM) ? gptr[0] : 0.f;     // G[0,s]

    int cc = 2;                                 // cc[1] = 2 (msf[0]==0 always)

#pragma unroll 1
    for (int i = 0; i < T_DIM - 1; ++i) {       // step t = i+1
        if (i >= 1) cc += 1 + (int)skip_lds[i - 1];

        // prefetch G[i+1, s] (i+1 <= 127)
        float gn = (s < S_DIM) ? gptr[(size_t)(i + 1) * N_DIM * C_DIM] : 0.f;

        float hs = fmaxf(v + g, LOG_TINY);
        if (s > cc) hs = LOG_TINY;              // unreachable mask

        if (s < S_DIM) hsbuf[i & 1][s] = hs;
        __syncthreads();

        if (s < S_DIM) {
            if (s == 0) {
                v = hs;
            } else {
                float a = logadd_(hs, hsbuf[i & 1][s - 1]);
                if (skip_s) a = logadd_(a, hsbuf[i & 1][s - 2]);
                v = a;
            }
        }
        g = gn;
    }

    // res[s] = v + G[T-1, s]   (final step has no clamp)
    if (s < S_DIM) resbuf[s] = v + g;
    __syncthreads();

    if (s == 0) {
        int tl = tlen[n];                       // 32..64
        float g1 = resbuf[2 * tl];              // res[L-1], L = 2*tl+1
        float g2 = resbuf[2 * tl - 1];          // res[L-2]
        out[n] = -(logadd_(g1, g2) / (float)tl);
    }
}

extern "C" void kernel_launch(void* const* d_in, const int* in_sizes, int n_in,
                              void* d_out, int out_size, void* d_ws, size_t ws_size,
                              hipStream_t stream) {
    const float* mask     = (const float*)d_in[0];   // (T,H,N)
    const float* classify = (const float*)d_in[1];   // (T,H,N,C)
    const int*   targets  = (const int*)d_in[2];     // (N,64)
    // d_in[3] = input_lengths (unused by reference)
    const int*   tlen     = (const int*)d_in[4];     // (N,)
    float*       out      = (float*)d_out;           // (N,)

    float* Gc = (float*)d_ws;                        // T*N*C*4 = 8 MiB scratch

    gc_kernel<<<dim3(T_DIM * N_DIM), dim3(256), 0, stream>>>(mask, classify, Gc);
    scan_kernel<<<dim3(N_DIM), dim3(192), 0, stream>>>(Gc, targets, tlen, out);
}

// Round 2
// 242.765 us; speedup vs baseline: 1.0979x; 1.0979x over previous
//
#include <hip/hip_runtime.h>
#include <math.h>

#define T_DIM 128
#define H_DIM 16
#define N_DIM 64
#define C_DIM 256
#define S_DIM 129   // 2*64+1
#define LOG_TINY (-87.336544750553109f)

__device__ __forceinline__ float logadd_(float a, float b) {
    float m = fmaxf(a, b);
    float d = fminf(a, b) - m;          // <= 0
    return m + __logf(1.0f + __expf(d));
}

// Kernel 1: for each (t, n): lse[c] = logsumexp_h(classify[t,h,n,c] + mask[t,h,n])
// then compact-gather the only classes the scan needs:
//   Gt[n][t][l] = lse[targets[n][l]]  (l=0..63)   Gb[n][t] = lse[blank=0]
// float4 loads; 134 MB read (HBM floor), 2.1 MB written.
__global__ __launch_bounds__(256) void gc_kernel(
    const float* __restrict__ mask,        // (T,H,N)
    const float* __restrict__ classify,    // (T,H,N,C)
    const int*   __restrict__ targets,     // (N,64)
    float* __restrict__ Gt,                // (N,T,64)
    float* __restrict__ Gb)                // (N,T)
{
    const int t  = blockIdx.x;             // 0..127
    const int ng = blockIdx.y;             // 0..15  (group of 4 n)
    const int nl = threadIdx.x >> 6;       // 0..3
    const int cg = threadIdx.x & 63;       // 0..63
    const int c  = cg * 4;
    const int n  = ng * 4 + nl;

    __shared__ float m_lds[H_DIM][4];      // mask[t,h,n] for the 4 n's
    __shared__ float lse_lds[4][C_DIM];

    if (threadIdx.x < 64) {
        int h  = threadIdx.x >> 2;
        int nn = threadIdx.x & 3;
        m_lds[h][nn] = mask[(t * H_DIM + h) * N_DIM + ng * 4 + nn];
    }
    __syncthreads();

    const float4* base = (const float4*)(classify +
        ((size_t)t * H_DIM * N_DIM + n) * C_DIM + c);
    const size_t hstride = (size_t)N_DIM * C_DIM / 4;   // float4 units

    float4 x[H_DIM];
#pragma unroll
    for (int h = 0; h < H_DIM; ++h) {
        float4 v = base[h * hstride];
        float  m = m_lds[h][nl];
        x[h] = make_float4(v.x + m, v.y + m, v.z + m, v.w + m);
    }
    float4 mx = make_float4(-3.4e38f, -3.4e38f, -3.4e38f, -3.4e38f);
#pragma unroll
    for (int h = 0; h < H_DIM; ++h) {
        mx.x = fmaxf(mx.x, x[h].x); mx.y = fmaxf(mx.y, x[h].y);
        mx.z = fmaxf(mx.z, x[h].z); mx.w = fmaxf(mx.w, x[h].w);
    }
    float4 s = make_float4(0.f, 0.f, 0.f, 0.f);
#pragma unroll
    for (int h = 0; h < H_DIM; ++h) {
        s.x += __expf(x[h].x - mx.x); s.y += __expf(x[h].y - mx.y);
        s.z += __expf(x[h].z - mx.z); s.w += __expf(x[h].w - mx.w);
    }
    lse_lds[nl][c + 0] = mx.x + __logf(s.x);
    lse_lds[nl][c + 1] = mx.y + __logf(s.y);
    lse_lds[nl][c + 2] = mx.z + __logf(s.z);
    lse_lds[nl][c + 3] = mx.w + __logf(s.w);
    __syncthreads();

    // gather phase: thread (nl, l) writes Gt[n][t][l]
    {
        int l  = cg;
        int tv = targets[n * 64 + l];
        Gt[((size_t)n * T_DIM + t) * 64 + l] = lse_lds[nl][tv];
        if (l == 0) Gb[n * T_DIM + t] = lse_lds[nl][0];
    }
}

// Kernel 2: one wave per n. Lane l owns lattice s=2l, 2l+1 (lane 63 also s=128).
// All G values preloaded to LDS; skip flags packed into a 64-bit ballot; the
// 127-step recursion is barrier-free (wave-synchronous, one shfl_up per step).
__global__ __launch_bounds__(64) void scan_kernel(
    const float* __restrict__ Gt,        // (N,T,64)
    const float* __restrict__ Gb,        // (N,T)
    const int*   __restrict__ targets,   // (N,64)
    const int*   __restrict__ tlen,      // (N,)
    float*       __restrict__ out)       // (N,)
{
    const int n = blockIdx.x;
    const int l = threadIdx.x;           // 0..63

    __shared__ float gt_lds[T_DIM * 64]; // [t][l]
    __shared__ float gb_lds[T_DIM];

    // preload all G for this n (coalesced, fully pipelined)
    const float* gsrc = Gt + (size_t)n * T_DIM * 64;
#pragma unroll 8
    for (int j = l; j < T_DIM * 64; j += 64) gt_lds[j] = gsrc[j];
    gb_lds[l]      = Gb[n * T_DIM + l];
    gb_lds[l + 64] = Gb[n * T_DIM + l + 64];

    int tgt_l = targets[n * 64 + l];
    int tgt_p = __shfl_up(tgt_l, 1, 64);
    unsigned long long D = __ballot(l > 0 && tgt_l != tgt_p);
    // bit l of D: skip flag for odd lattice pos s = 2l-1's successor semantics:
    //   skip for s=2l+1 <=> (tgt[l] != tgt[l-1]) <=> bit l
    const int skip1 = (int)((D >> l) & 1ULL) && (l > 0);

    __syncthreads();

    // v state: s=2l (v0), s=2l+1 (v1), s=128 on lane 63 (v2)
    float v0 = (l == 0) ? 0.f : -1e30f;
    float v1 = (l == 0) ? 0.f : -1e30f;
    float v2 = -1e30f;                   // lane 63 only

    int cc = 2;                          // cc at step i=0

#pragma unroll 1
    for (int i = 0; i < T_DIM - 1; ++i) {
        if (i >= 1)
            cc += 1 + (int)((i & 1) ? 0ULL : ((D >> (i >> 1)) & 1ULL));

        float gb = gb_lds[i];
        float gt = gt_lds[i * 64 + l];

        float hs0 = fmaxf(v0 + gb, LOG_TINY);
        if (2 * l > cc) hs0 = LOG_TINY;
        float hs1 = fmaxf(v1 + gt, LOG_TINY);
        if (2 * l + 1 > cc) hs1 = LOG_TINY;
        float hs2 = fmaxf(v2 + gb, LOG_TINY);
        if (128 > cc) hs2 = LOG_TINY;    // s=128 (lane 63's value used)

        float p1 = __shfl_up(hs1, 1, 64);   // hs[2l-1]

        // s=2l (even, no skip): v0' = logadd(hs0, hs[2l-1])
        v0 = (l == 0) ? hs0 : logadd_(hs0, p1);
        // s=2l+1: v1' = logadd(hs1, hs0) [+ hs[2l-1] if skip]
        float a = logadd_(hs1, hs0);
        if (skip1) a = logadd_(a, p1);
        v1 = a;
        // s=128 (lane 63): v2' = logadd(hs2, hs[127]=own hs1)
        v2 = logadd_(hs2, hs1);
    }

    // res[s] = v[s] + G[T-1, s]
    float gb_f = gb_lds[T_DIM - 1];
    float gt_f = gt_lds[(T_DIM - 1) * 64 + l];
    float res0 = v0 + gb_f;              // s = 2l
    float res1 = v1 + gt_f;              // s = 2l+1
    float res2 = v2 + gb_f;              // s = 128 (lane 63)

    int tl = tlen[n];                    // 32..64
    float g1 = (tl == 64) ? __shfl(res2, 63, 64) : __shfl(res0, tl, 64);
    float g2 = __shfl(res1, tl - 1, 64); // s = 2tl-1
    if (l == 0)
        out[n] = -(logadd_(g1, g2) / (float)tl);
}

extern "C" void kernel_launch(void* const* d_in, const int* in_sizes, int n_in,
                              void* d_out, int out_size, void* d_ws, size_t ws_size,
                              hipStream_t stream) {
    const float* mask     = (const float*)d_in[0];   // (T,H,N)
    const float* classify = (const float*)d_in[1];   // (T,H,N,C)
    const int*   targets  = (const int*)d_in[2];     // (N,64)
    // d_in[3] = input_lengths (unused by reference)
    const int*   tlen     = (const int*)d_in[4];     // (N,)
    float*       out      = (float*)d_out;           // (N,)

    float* Gt = (float*)d_ws;                              // 64*128*64*4 = 2 MiB
    float* Gb = (float*)((char*)d_ws + (size_t)N_DIM * T_DIM * 64 * 4); // 32 KiB

    gc_kernel<<<dim3(T_DIM, 16), dim3(256), 0, stream>>>(mask, classify, targets, Gt, Gb);
    scan_kernel<<<dim3(N_DIM), dim3(64), 0, stream>>>(Gt, Gb, targets, tlen, out);
}